// Round 1
// baseline (541.980 us; speedup 1.0000x reference)
//
#include <hip/hip_runtime.h>
#include <hip/hip_bf16.h>

#define NEG_SLOPE 0.01f
#define CH 4096            // edges per block in hist/scatter (LDS-aggregated)
#define PAD 16             // 64B stride for contended global counters
// bucket sort: rows per bucket = 256 (bucket id = row >> 8)
// Packing assumes col < 2^24 and rows-per-bucket = 256 (rowlow in top 8 bits).
// finalize additionally orders each row's edges by col tile (col>>13) so that
// concurrent gather threads sweep h1 in ~1MB tile phases -> L2-resident gathers.
#define NT 16              // col tiles (col < 2^17 -> tile = col>>13 in [0,16))
#define TILE_SHIFT 13
#define KEYS (256 * NT)    // finalize counting-sort bins: (rowlow, tile)

__device__ __forceinline__ void atomAddF(float* p, float v) {
    unsafeAtomicAdd(p, v);   // HW global_atomic_add_f32 (avoids CAS fallback)
}

// ---- phase 1: bucket histogram, block-aggregated, padded flush ----------
__global__ void bucket_hist_kernel(const int* __restrict__ row, int* __restrict__ bhist_p,
                                   int E, int NB) {
    __shared__ int lh[512];
    for (int t = threadIdx.x; t < 512; t += 256) lh[t] = 0;
    __syncthreads();
    int base = blockIdx.x * CH;
    int end = min(base + CH, E);
    for (int e = base + threadIdx.x; e < end; e += 256)
        atomicAdd(&lh[row[e] >> 8], 1);
    __syncthreads();
    for (int t = threadIdx.x; t < NB; t += 256)
        if (lh[t]) atomicAdd(&bhist_p[t * PAD], lh[t]);
}

// ---- phase 2: exclusive scan of bucket counts (NB <= 512), init cursors -
__global__ void bucket_scan_kernel(const int* __restrict__ bhist_p, int* __restrict__ bbase,
                                   int* __restrict__ bcursor_p, int* __restrict__ rowptr,
                                   int NB, int N, int E) {
    __shared__ int s[512];
    int t = threadIdx.x;
    int v = (t < NB) ? bhist_p[t * PAD] : 0;
    s[t] = v;
    __syncthreads();
    for (int off = 1; off < 512; off <<= 1) {
        int x = (t >= off) ? s[t - off] : 0;
        __syncthreads();
        s[t] += x;
        __syncthreads();
    }
    if (t < NB) { bbase[t] = s[t] - v; bcursor_p[t * PAD] = s[t] - v; }
    if (t == 0) { bbase[NB] = E; rowptr[N] = E; }
}

// ---- phase 3: block-aggregated scatter into bucket-contiguous staging ---
// One global atomic per (block, non-empty bucket); per-edge position via LDS.
// staging word0 = col | (row&255)<<24 ; word1 = attr bits
__global__ void bucket_scatter_kernel(const int* __restrict__ row, const int* __restrict__ col,
                                      const float* __restrict__ attr, int* __restrict__ bcursor_p,
                                      int2* __restrict__ staging, int E, int NB) {
    __shared__ int lh[512];
    __shared__ int lbase[512];
    __shared__ int lcur[512];
    for (int t = threadIdx.x; t < 512; t += 256) { lh[t] = 0; lcur[t] = 0; }
    __syncthreads();
    int base = blockIdx.x * CH;
    int end = min(base + CH, E);
    for (int e = base + threadIdx.x; e < end; e += 256)
        atomicAdd(&lh[row[e] >> 8], 1);
    __syncthreads();
    for (int t = threadIdx.x; t < NB; t += 256)
        if (lh[t]) lbase[t] = atomicAdd(&bcursor_p[t * PAD], lh[t]);
    __syncthreads();
    for (int e = base + threadIdx.x; e < end; e += 256) {
        int r = row[e], c = col[e];
        int bk = r >> 8;
        int pos = lbase[bk] + atomicAdd(&lcur[bk], 1);
        staging[pos] = make_int2(c | ((r & 255) << 24), __float_as_int(attr[e]));
    }
}

// ---- phase 4: per-bucket finalize: rowptr, dinv, sorted CSR -------------
// One block per bucket; block owns its 256 rows exclusively -> no global atomics.
// Counting sort key = (rowlow, col>>13): edges stay row-contiguous (CSR intact)
// but within each row are ordered by col tile, so the gather phase sweeps h1
// in ~1MB tile windows that stay L2-resident.
// sorted.y is pre-scaled: pre = -dinv[row] * attr  (gather multiplies by dinv[col])
__global__ void bucket_finalize_kernel(const int* __restrict__ bbase,
                                       const int2* __restrict__ staging,
                                       int2* __restrict__ sorted, int* __restrict__ rowptr,
                                       float* __restrict__ dinv, int N) {
    __shared__ int lcount[KEYS];     // per-(row,tile) count -> exclusive scan -> cursor
    __shared__ int lsum[256];        // per-row totals for cross-row scan
    __shared__ float ldeg[256];
    __shared__ float sdinv[256];
    int t = threadIdx.x;
    int b = blockIdx.x;
    int base = bbase[b], end = bbase[b + 1];
    for (int k = t; k < KEYS; k += 256) lcount[k] = 0;
    ldeg[t] = 0.f;
    __syncthreads();
    for (int e = base + t; e < end; e += 256) {
        int2 w = staging[e];
        int rl = (w.x >> 24) & 255;
        int tile = (w.x & 0xFFFFFF) >> TILE_SHIFT;
        atomicAdd(&lcount[rl * NT + tile], 1);
        atomicAdd(&ldeg[rl], __int_as_float(w.y));
    }
    __syncthreads();
    // serial exclusive scan of this row's NT bins (thread t owns keys [t*NT, t*NT+NT))
    int vals[NT];
    int s = 0;
#pragma unroll
    for (int j = 0; j < NT; j++) { vals[j] = s; s += lcount[t * NT + j]; }
    lsum[t] = s;
    __syncthreads();
    // inclusive Hillis-Steele scan over the 256 row totals
    for (int off = 1; off < 256; off <<= 1) {
        int x = (t >= off) ? lsum[t - off] : 0;
        __syncthreads();
        lsum[t] += x;
        __syncthreads();
    }
    int rowexcl = lsum[t] - s;       // exclusive prefix at the start of row t
#pragma unroll
    for (int j = 0; j < NT; j++) lcount[t * NT + j] = rowexcl + vals[j];  // -> cursors
    int grow = (b << 8) + t;
    float d = ldeg[t];
    float di = d > 0.f ? rsqrtf(d) : 0.f;
    sdinv[t] = di;
    if (grow < N) {
        rowptr[grow] = base + rowexcl;
        dinv[grow] = di;
    }
    __syncthreads();
    for (int e = base + t; e < end; e += 256) {
        int2 w = staging[e];
        int rl = (w.x >> 24) & 255;
        int c = w.x & 0xFFFFFF;
        int key = rl * NT + (c >> TILE_SHIFT);
        int pos = base + atomicAdd(&lcount[key], 1);
        float pre = -sdinv[rl] * __int_as_float(w.y);
        sorted[pos] = make_int2(c, __float_as_int(pre));   // {col, pre}
    }
}

// ---- h1 = leaky_relu(x @ w1 + b1), x:(N,20) w:(20,32) -------------------
__global__ void h1_kernel(const float* __restrict__ x, const float* __restrict__ w,
                          const float* __restrict__ b, float* __restrict__ h1, int N) {
    __shared__ float ws[20 * 32];
    __shared__ float bs[32];
    for (int t = threadIdx.x; t < 640; t += blockDim.x) ws[t] = w[t];
    if (threadIdx.x < 32) bs[threadIdx.x] = b[threadIdx.x];
    __syncthreads();
    int i = blockIdx.x * blockDim.x + threadIdx.x;
    if (i >= N) return;
    float xi[20];
#pragma unroll
    for (int k = 0; k < 20; k++) xi[k] = x[i * 20 + k];
    float acc[32];
#pragma unroll
    for (int j = 0; j < 32; j++) acc[j] = bs[j];
#pragma unroll
    for (int k = 0; k < 20; k++) {
        float a = xi[k];
#pragma unroll
        for (int j = 0; j < 32; j++) acc[j] += a * ws[k * 32 + j];
    }
#pragma unroll
    for (int j = 0; j < 32; j++) {
        float v = acc[j];
        h1[(long)i * 32 + j] = v > 0.f ? v : v * NEG_SLOPE;
    }
}

// ---- gather-propagate + cw accumulation (4x unrolled for MLP) -----------
// p1[i] = sum_{e in CSR row i} (pre * dinv[col]) * h1[col]
// part==0 lane also does cw[col] += nm (for the pooled layer-3 path).
// 8 threads per node, each owning a float4 slice of the 32 features.
__global__ void gather_kernel(const int* __restrict__ rowptr, const int2* __restrict__ sorted,
                              const float* __restrict__ dinv, const float* __restrict__ h1,
                              float* __restrict__ p1g, float* __restrict__ cw, int N) {
    long idx = (long)blockIdx.x * blockDim.x + threadIdx.x;
    int node = (int)(idx >> 3);
    int part = (int)(idx & 7);
    if (node >= N) return;
    int s0 = rowptr[node], s1 = rowptr[node + 1];
    const float4* h1v = (const float4*)h1;
    float4 acc = make_float4(0.f, 0.f, 0.f, 0.f);
    int e = s0;
    for (; e + 4 <= s1; e += 4) {
        int2 q0 = sorted[e], q1 = sorted[e + 1], q2 = sorted[e + 2], q3 = sorted[e + 3];
        int c0 = q0.x, c1 = q1.x, c2 = q2.x, c3 = q3.x;
        float d0 = dinv[c0], d1 = dinv[c1], d2 = dinv[c2], d3 = dinv[c3];
        float4 v0 = h1v[(long)c0 * 8 + part];
        float4 v1 = h1v[(long)c1 * 8 + part];
        float4 v2 = h1v[(long)c2 * 8 + part];
        float4 v3 = h1v[(long)c3 * 8 + part];
        float n0 = __int_as_float(q0.y) * d0;
        float n1 = __int_as_float(q1.y) * d1;
        float n2 = __int_as_float(q2.y) * d2;
        float n3 = __int_as_float(q3.y) * d3;
        if (part == 0) {
            atomAddF(&cw[c0], n0); atomAddF(&cw[c1], n1);
            atomAddF(&cw[c2], n2); atomAddF(&cw[c3], n3);
        }
        acc.x += n0 * v0.x + n1 * v1.x + n2 * v2.x + n3 * v3.x;
        acc.y += n0 * v0.y + n1 * v1.y + n2 * v2.y + n3 * v3.y;
        acc.z += n0 * v0.z + n1 * v1.z + n2 * v2.z + n3 * v3.z;
        acc.w += n0 * v0.w + n1 * v1.w + n2 * v2.w + n3 * v3.w;
    }
    for (; e < s1; e++) {
        int2 q = sorted[e];
        int c = q.x;
        float nm = __int_as_float(q.y) * dinv[c];
        if (part == 0) atomAddF(&cw[c], nm);
        float4 v = h1v[(long)c * 8 + part];
        acc.x += nm * v.x; acc.y += nm * v.y; acc.z += nm * v.z; acc.w += nm * v.w;
    }
    ((float4*)p1g)[(long)node * 8 + part] = acc;
}

// ---- h2 = leaky_relu(h1 @ w2_0 + p1 @ w2_1 + b2), 32 -> 64 --------------
__global__ void __launch_bounds__(256, 1)
h2_kernel(const float* __restrict__ h1, const float* __restrict__ p1,
          const float* __restrict__ w0, const float* __restrict__ w1,
          const float* __restrict__ b, float* __restrict__ h2, int N) {
    __shared__ float w0s[32 * 64];
    __shared__ float w1s[32 * 64];
    __shared__ float bs[64];
    for (int t = threadIdx.x; t < 2048; t += blockDim.x) { w0s[t] = w0[t]; w1s[t] = w1[t]; }
    if (threadIdx.x < 64) bs[threadIdx.x] = b[threadIdx.x];
    __syncthreads();
    int i = blockIdx.x * blockDim.x + threadIdx.x;
    if (i >= N) return;
    const float4* w0v = (const float4*)w0s;   // [k*16 + j4]
    const float4* w1v = (const float4*)w1s;
    const float4* bv  = (const float4*)bs;
    float4 acc[16];
#pragma unroll
    for (int j4 = 0; j4 < 16; j4++) acc[j4] = bv[j4];
    const float4* h1v = (const float4*)(h1 + (long)i * 32);
    const float4* p1v = (const float4*)(p1 + (long)i * 32);
#pragma unroll
    for (int k4 = 0; k4 < 8; k4++) {
        float4 a = h1v[k4];
        float4 p = p1v[k4];
        float av[4] = {a.x, a.y, a.z, a.w};
        float pv[4] = {p.x, p.y, p.z, p.w};
#pragma unroll
        for (int s = 0; s < 4; s++) {
            int k = k4 * 4 + s;
            float aa = av[s], pp = pv[s];
#pragma unroll
            for (int j4 = 0; j4 < 16; j4++) {
                float4 w0r = w0v[k * 16 + j4];
                float4 w1r = w1v[k * 16 + j4];
                acc[j4].x += aa * w0r.x + pp * w1r.x;
                acc[j4].y += aa * w0r.y + pp * w1r.y;
                acc[j4].z += aa * w0r.z + pp * w1r.z;
                acc[j4].w += aa * w0r.w + pp * w1r.w;
            }
        }
    }
    float4* out = (float4*)(h2 + (long)i * 64);
#pragma unroll
    for (int j4 = 0; j4 < 16; j4++) {
        float4 v = acc[j4];
        v.x = v.x > 0.f ? v.x : v.x * NEG_SLOPE;
        v.y = v.y > 0.f ? v.y : v.y * NEG_SLOPE;
        v.z = v.z > 0.f ? v.z : v.z * NEG_SLOPE;
        v.w = v.w > 0.f ? v.w : v.w * NEG_SLOPE;
        out[j4] = v;
    }
}

// ---- fused pooled sums over h2 ------------------------------------------
// sbuf[j]    += sum_i h2[i][j]           (plain mean path, w3_0)
// sbuf[64+j] += sum_i cw[i] * h2[i][j]   (propagated mean path, w3_1)
__global__ void sum2_kernel(const float* __restrict__ h2, const float* __restrict__ cw,
                            float* __restrict__ sbuf, long total) {
    long tid = (long)blockIdx.x * blockDim.x + threadIdx.x;
    long stride = (long)gridDim.x * blockDim.x;   // multiple of 64
    float a1 = 0.f, a2 = 0.f;
    for (long idx = tid; idx < total; idx += stride) {
        float v = h2[idx];
        a1 += v;
        a2 += cw[idx >> 6] * v;
    }
    __shared__ float red1[256];
    __shared__ float red2[256];
    red1[threadIdx.x] = a1;
    red2[threadIdx.x] = a2;
    __syncthreads();
    if (threadIdx.x < 64) {
        float s1 = red1[threadIdx.x] + red1[threadIdx.x + 64] + red1[threadIdx.x + 128] + red1[threadIdx.x + 192];
        float s2 = red2[threadIdx.x] + red2[threadIdx.x + 64] + red2[threadIdx.x + 128] + red2[threadIdx.x + 192];
        atomAddF(&sbuf[threadIdx.x], s1);
        atomAddF(&sbuf[64 + threadIdx.x], s2);
    }
}

// ---- pooled = (s1/N)@w30 + (s2/N)@w31 + b3; out = log_softmax -----------
__global__ void final_kernel(const float* __restrict__ sbuf,
                             const float* __restrict__ w30, const float* __restrict__ w31,
                             const float* __restrict__ b3, float* __restrict__ out, float invN) {
    if (threadIdx.x != 0 || blockIdx.x != 0) return;
    const float* s1 = sbuf;
    const float* s2 = sbuf + 64;
    float p[2];
    for (int c = 0; c < 2; c++) {
        float a = 0.f;
        for (int k = 0; k < 64; k++) a += s1[k] * w30[k * 2 + c] + s2[k] * w31[k * 2 + c];
        p[c] = a * invN + b3[c];
    }
    float m = fmaxf(p[0], p[1]);
    float lse = m + logf(expf(p[0] - m) + expf(p[1] - m));
    out[0] = p[0] - lse;
    out[1] = p[1] - lse;
}

extern "C" void kernel_launch(void* const* d_in, const int* in_sizes, int n_in,
                              void* d_out, int out_size, void* d_ws, size_t ws_size,
                              hipStream_t stream) {
    const float* x    = (const float*)d_in[0];
    const int*   ei   = (const int*)d_in[1];
    const float* attr = (const float*)d_in[2];
    const float* w1_0 = (const float*)d_in[3];
    const float* b1   = (const float*)d_in[4];
    const float* w2_0 = (const float*)d_in[5];
    const float* w2_1 = (const float*)d_in[6];
    const float* b2   = (const float*)d_in[7];
    const float* w3_0 = (const float*)d_in[8];
    const float* w3_1 = (const float*)d_in[9];
    const float* b3   = (const float*)d_in[10];

    const int N = in_sizes[0] / 20;   // 100000
    const int E = in_sizes[2];        // 3200000
    const int* row = ei;
    const int* col = ei + E;
    const int NB = (N + 255) >> 8;    // 391 buckets (<= 512)

    // workspace layout (words)
    long big = (long)(2L * E > 64L * N ? 2L * E : 64L * N);
    float* ws = (float*)d_ws;
    float* dinv     = ws;                          // N
    float* cw       = ws + N;                      // N
    int*   rowptr   = (int*)(ws + 2L * N);         // N+1 (alloc N+4)
    int*   bhist_p  = (int*)(ws + 3L * N + 4);     // 512*PAD
    int*   bbase    = (int*)(ws + 3L * N + 4 + 512L * PAD);          // 513 (alloc 516)
    int*   bcursor_p= (int*)(ws + 3L * N + 520 + 512L * PAD);        // 512*PAD
    float* sbuf     = ws + 3L * N + 520 + 1024L * PAD;               // 128
    float* regA     = ws + 3L * N + 648 + 1024L * PAD;  // big: staging, then h1+p1
    float* regB     = regA + big;                       // big: sorted, then h2

    int2*  staging = (int2*)regA;               // dead after finalize
    float* h1      = regA;                      // overlays staging
    float* p1      = regA + 32L * N;
    int2*  sorted  = (int2*)regB;               // dead after gather
    float* h2      = regB;                      // overlays sorted

    // zero accumulated regions (ws is poisoned before every launch)
    hipMemsetAsync(bhist_p, 0, 512 * PAD * 4, stream);
    hipMemsetAsync(cw, 0, (size_t)N * 4, stream);
    hipMemsetAsync(sbuf, 0, 128 * 4, stream);

    const int B = 256;
    const int NCH = (E + CH - 1) / CH;   // chunk-blocks for hist/scatter
    bucket_hist_kernel<<<NCH, B, 0, stream>>>(row, bhist_p, E, NB);
    bucket_scan_kernel<<<1, 512, 0, stream>>>(bhist_p, bbase, bcursor_p, rowptr, NB, N, E);
    bucket_scatter_kernel<<<NCH, B, 0, stream>>>(row, col, attr, bcursor_p, staging, E, NB);
    bucket_finalize_kernel<<<NB, 256, 0, stream>>>(bbase, staging, sorted, rowptr, dinv, N);
    h1_kernel<<<(N + B - 1) / B, B, 0, stream>>>(x, w1_0, b1, h1, N);
    {
        long t = (long)N * 8;
        gather_kernel<<<(int)((t + B - 1) / B), B, 0, stream>>>(rowptr, sorted, dinv, h1, p1, cw, N);
    }
    h2_kernel<<<(N + B - 1) / B, B, 0, stream>>>(h1, p1, w2_0, w2_1, b2, h2, N);
    sum2_kernel<<<256, B, 0, stream>>>(h2, cw, sbuf, (long)N * 64);
    final_kernel<<<1, 64, 0, stream>>>(sbuf, w3_0, w3_1, b3, (float*)d_out, 1.0f / (float)N);
}

// Round 2
// 537.450 us; speedup vs baseline: 1.0084x; 1.0084x over previous
//
#include <hip/hip_runtime.h>
#include <hip/hip_bf16.h>

#define NEG_SLOPE 0.01f
#define CH 4096            // edges per block in hist/scatter (LDS-aggregated)
#define PAD 16             // 64B stride for contended global counters
// bucket sort: rows per bucket = 256 (bucket id = row >> 8)
// Packing assumes col < 2^24 and rows-per-bucket = 256 (rowlow in top 8 bits).
// finalize orders each row's edges by col tile (col>>13): with bf16 h1 rows
// (64B) a tile is 512KB, so the gather's instantaneous footprint can sit in L2.
#define NT 16              // col tiles (col < 2^17 -> tile = col>>13 in [0,16))
#define TILE_SHIFT 13
#define KEYS (256 * NT)    // finalize counting-sort bins: (rowlow, tile)

__device__ __forceinline__ void atomAddF(float* p, float v) {
    unsafeAtomicAdd(p, v);   // HW global_atomic_add_f32 (avoids CAS fallback)
}

// bf16 pack/unpack (round-to-nearest-even; finite values only)
__device__ __forceinline__ unsigned bf16rn(float f) {
    unsigned u = __float_as_uint(f);
    return (u + 0x7FFFu + ((u >> 16) & 1u)) >> 16;
}
__device__ __forceinline__ unsigned pack2(float a, float b) {
    return bf16rn(a) | (bf16rn(b) << 16);
}
__device__ __forceinline__ float blo(unsigned u) { return __uint_as_float(u << 16); }
__device__ __forceinline__ float bhi(unsigned u) { return __uint_as_float(u & 0xFFFF0000u); }

// ---- phase 1: bucket histogram, block-aggregated, padded flush ----------
__global__ void bucket_hist_kernel(const int* __restrict__ row, int* __restrict__ bhist_p,
                                   int E, int NB) {
    __shared__ int lh[512];
    for (int t = threadIdx.x; t < 512; t += 256) lh[t] = 0;
    __syncthreads();
    int base = blockIdx.x * CH;
    int end = min(base + CH, E);
    for (int e = base + threadIdx.x; e < end; e += 256)
        atomicAdd(&lh[row[e] >> 8], 1);
    __syncthreads();
    for (int t = threadIdx.x; t < NB; t += 256)
        if (lh[t]) atomicAdd(&bhist_p[t * PAD], lh[t]);
}

// ---- phase 2: exclusive scan of bucket counts (NB <= 512), init cursors -
__global__ void bucket_scan_kernel(const int* __restrict__ bhist_p, int* __restrict__ bbase,
                                   int* __restrict__ bcursor_p, int* __restrict__ rowptr,
                                   int NB, int N, int E) {
    __shared__ int s[512];
    int t = threadIdx.x;
    int v = (t < NB) ? bhist_p[t * PAD] : 0;
    s[t] = v;
    __syncthreads();
    for (int off = 1; off < 512; off <<= 1) {
        int x = (t >= off) ? s[t - off] : 0;
        __syncthreads();
        s[t] += x;
        __syncthreads();
    }
    if (t < NB) { bbase[t] = s[t] - v; bcursor_p[t * PAD] = s[t] - v; }
    if (t == 0) { bbase[NB] = E; rowptr[N] = E; }
}

// ---- phase 3: block-aggregated scatter into bucket-contiguous staging ---
__global__ void bucket_scatter_kernel(const int* __restrict__ row, const int* __restrict__ col,
                                      const float* __restrict__ attr, int* __restrict__ bcursor_p,
                                      int2* __restrict__ staging, int E, int NB) {
    __shared__ int lh[512];
    __shared__ int lbase[512];
    __shared__ int lcur[512];
    for (int t = threadIdx.x; t < 512; t += 256) { lh[t] = 0; lcur[t] = 0; }
    __syncthreads();
    int base = blockIdx.x * CH;
    int end = min(base + CH, E);
    for (int e = base + threadIdx.x; e < end; e += 256)
        atomicAdd(&lh[row[e] >> 8], 1);
    __syncthreads();
    for (int t = threadIdx.x; t < NB; t += 256)
        if (lh[t]) lbase[t] = atomicAdd(&bcursor_p[t * PAD], lh[t]);
    __syncthreads();
    for (int e = base + threadIdx.x; e < end; e += 256) {
        int r = row[e], c = col[e];
        int bk = r >> 8;
        int pos = lbase[bk] + atomicAdd(&lcur[bk], 1);
        staging[pos] = make_int2(c | ((r & 255) << 24), __float_as_int(attr[e]));
    }
}

// ---- phase 4: per-bucket finalize: rowptr, dinv, sorted CSR -------------
// Counting sort key = (rowlow, col>>13): CSR intact, rows tile-ordered.
// sorted.y is pre-scaled: pre = -dinv[row] * attr  (dinv[col] is baked into h1b)
__global__ void bucket_finalize_kernel(const int* __restrict__ bbase,
                                       const int2* __restrict__ staging,
                                       int2* __restrict__ sorted, int* __restrict__ rowptr,
                                       float* __restrict__ dinv, int N) {
    __shared__ int lcount[KEYS];     // per-(row,tile) count -> exclusive scan -> cursor
    __shared__ int lsum[256];        // per-row totals for cross-row scan
    __shared__ float ldeg[256];
    __shared__ float sdinv[256];
    int t = threadIdx.x;
    int b = blockIdx.x;
    int base = bbase[b], end = bbase[b + 1];
    for (int k = t; k < KEYS; k += 256) lcount[k] = 0;
    ldeg[t] = 0.f;
    __syncthreads();
    for (int e = base + t; e < end; e += 256) {
        int2 w = staging[e];
        int rl = (w.x >> 24) & 255;
        int tile = (w.x & 0xFFFFFF) >> TILE_SHIFT;
        atomicAdd(&lcount[rl * NT + tile], 1);
        atomicAdd(&ldeg[rl], __int_as_float(w.y));
    }
    __syncthreads();
    int vals[NT];
    int s = 0;
#pragma unroll
    for (int j = 0; j < NT; j++) { vals[j] = s; s += lcount[t * NT + j]; }
    lsum[t] = s;
    __syncthreads();
    for (int off = 1; off < 256; off <<= 1) {
        int x = (t >= off) ? lsum[t - off] : 0;
        __syncthreads();
        lsum[t] += x;
        __syncthreads();
    }
    int rowexcl = lsum[t] - s;
#pragma unroll
    for (int j = 0; j < NT; j++) lcount[t * NT + j] = rowexcl + vals[j];  // -> cursors
    int grow = (b << 8) + t;
    float d = ldeg[t];
    float di = d > 0.f ? rsqrtf(d) : 0.f;
    sdinv[t] = di;
    if (grow < N) {
        rowptr[grow] = base + rowexcl;
        dinv[grow] = di;
    }
    __syncthreads();
    for (int e = base + t; e < end; e += 256) {
        int2 w = staging[e];
        int rl = (w.x >> 24) & 255;
        int c = w.x & 0xFFFFFF;
        int key = rl * NT + (c >> TILE_SHIFT);
        int pos = base + atomicAdd(&lcount[key], 1);
        float pre = -sdinv[rl] * __int_as_float(w.y);
        sorted[pos] = make_int2(c, __float_as_int(pre));   // {col, pre}
    }
}

// ---- h1 = leaky_relu(x @ w1 + b1); also h1b = bf16(dinv[i] * h1) --------
// h1b row = 32 bf16 = 64B = 4 uint4; feature 2k low half, 2k+1 high half.
__global__ void h1_kernel(const float* __restrict__ x, const float* __restrict__ w,
                          const float* __restrict__ b, const float* __restrict__ dinv,
                          float* __restrict__ h1, uint4* __restrict__ h1b, int N) {
    __shared__ float ws[20 * 32];
    __shared__ float bs[32];
    for (int t = threadIdx.x; t < 640; t += blockDim.x) ws[t] = w[t];
    if (threadIdx.x < 32) bs[threadIdx.x] = b[threadIdx.x];
    __syncthreads();
    int i = blockIdx.x * blockDim.x + threadIdx.x;
    if (i >= N) return;
    float xi[20];
#pragma unroll
    for (int k = 0; k < 20; k++) xi[k] = x[i * 20 + k];
    float acc[32];
#pragma unroll
    for (int j = 0; j < 32; j++) acc[j] = bs[j];
#pragma unroll
    for (int k = 0; k < 20; k++) {
        float a = xi[k];
#pragma unroll
        for (int j = 0; j < 32; j++) acc[j] += a * ws[k * 32 + j];
    }
#pragma unroll
    for (int j = 0; j < 32; j++) {
        float v = acc[j];
        acc[j] = v > 0.f ? v : v * NEG_SLOPE;
    }
    float4* h1v = (float4*)(h1 + (long)i * 32);
#pragma unroll
    for (int j4 = 0; j4 < 8; j4++)
        h1v[j4] = make_float4(acc[j4 * 4], acc[j4 * 4 + 1], acc[j4 * 4 + 2], acc[j4 * 4 + 3]);
    float di = dinv[i];
    unsigned u[16];
#pragma unroll
    for (int k = 0; k < 16; k++) u[k] = pack2(di * acc[2 * k], di * acc[2 * k + 1]);
#pragma unroll
    for (int q = 0; q < 4; q++)
        h1b[(long)i * 4 + q] = make_uint4(u[4 * q], u[4 * q + 1], u[4 * q + 2], u[4 * q + 3]);
}

// ---- gather-propagate + presum accumulation -----------------------------
// p1[i] = sum_{e in CSR row i} pre_e * h1b[col_e]   (dinv[col] baked into h1b)
// part==0 lane also does presum[col] += pre (dinv folded in at sum2).
// 4 threads per node, each owning 8 bf16 features (one uint4 = 64B/row total).
__global__ void gather_kernel(const int* __restrict__ rowptr, const int2* __restrict__ sorted,
                              const uint4* __restrict__ h1b, uint4* __restrict__ p1b,
                              float* __restrict__ presum, int N) {
    long idx = (long)blockIdx.x * blockDim.x + threadIdx.x;
    int node = (int)(idx >> 2);
    int part = (int)(idx & 3);
    if (node >= N) return;
    int s0 = rowptr[node], s1 = rowptr[node + 1];
    float acc[8];
#pragma unroll
    for (int k = 0; k < 8; k++) acc[k] = 0.f;
    int e = s0;
    for (; e + 4 <= s1; e += 4) {
        int2 q0 = sorted[e], q1 = sorted[e + 1], q2 = sorted[e + 2], q3 = sorted[e + 3];
        float n0 = __int_as_float(q0.y), n1 = __int_as_float(q1.y);
        float n2 = __int_as_float(q2.y), n3 = __int_as_float(q3.y);
        uint4 v0 = h1b[(long)q0.x * 4 + part];
        uint4 v1 = h1b[(long)q1.x * 4 + part];
        uint4 v2 = h1b[(long)q2.x * 4 + part];
        uint4 v3 = h1b[(long)q3.x * 4 + part];
        if (part == 0) {
            atomAddF(&presum[q0.x], n0); atomAddF(&presum[q1.x], n1);
            atomAddF(&presum[q2.x], n2); atomAddF(&presum[q3.x], n3);
        }
        acc[0] += n0 * blo(v0.x) + n1 * blo(v1.x) + n2 * blo(v2.x) + n3 * blo(v3.x);
        acc[1] += n0 * bhi(v0.x) + n1 * bhi(v1.x) + n2 * bhi(v2.x) + n3 * bhi(v3.x);
        acc[2] += n0 * blo(v0.y) + n1 * blo(v1.y) + n2 * blo(v2.y) + n3 * blo(v3.y);
        acc[3] += n0 * bhi(v0.y) + n1 * bhi(v1.y) + n2 * bhi(v2.y) + n3 * bhi(v3.y);
        acc[4] += n0 * blo(v0.z) + n1 * blo(v1.z) + n2 * blo(v2.z) + n3 * blo(v3.z);
        acc[5] += n0 * bhi(v0.z) + n1 * bhi(v1.z) + n2 * bhi(v2.z) + n3 * bhi(v3.z);
        acc[6] += n0 * blo(v0.w) + n1 * blo(v1.w) + n2 * blo(v2.w) + n3 * blo(v3.w);
        acc[7] += n0 * bhi(v0.w) + n1 * bhi(v1.w) + n2 * bhi(v2.w) + n3 * bhi(v3.w);
    }
    for (; e < s1; e++) {
        int2 q = sorted[e];
        float nm = __int_as_float(q.y);
        if (part == 0) atomAddF(&presum[q.x], nm);
        uint4 v = h1b[(long)q.x * 4 + part];
        acc[0] += nm * blo(v.x); acc[1] += nm * bhi(v.x);
        acc[2] += nm * blo(v.y); acc[3] += nm * bhi(v.y);
        acc[4] += nm * blo(v.z); acc[5] += nm * bhi(v.z);
        acc[6] += nm * blo(v.w); acc[7] += nm * bhi(v.w);
    }
    p1b[(long)node * 4 + part] = make_uint4(pack2(acc[0], acc[1]), pack2(acc[2], acc[3]),
                                            pack2(acc[4], acc[5]), pack2(acc[6], acc[7]));
}

// ---- h2 = leaky_relu(h1 @ w2_0 + p1 @ w2_1 + b2), 32 -> 64 --------------
// h1 fp32, p1 bf16-packed (same layout as h1b).
__global__ void __launch_bounds__(256, 1)
h2_kernel(const float* __restrict__ h1, const uint4* __restrict__ p1b,
          const float* __restrict__ w0, const float* __restrict__ w1,
          const float* __restrict__ b, float* __restrict__ h2, int N) {
    __shared__ float w0s[32 * 64];
    __shared__ float w1s[32 * 64];
    __shared__ float bs[64];
    for (int t = threadIdx.x; t < 2048; t += blockDim.x) { w0s[t] = w0[t]; w1s[t] = w1[t]; }
    if (threadIdx.x < 64) bs[threadIdx.x] = b[threadIdx.x];
    __syncthreads();
    int i = blockIdx.x * blockDim.x + threadIdx.x;
    if (i >= N) return;
    const float4* w0v = (const float4*)w0s;   // [k*16 + j4]
    const float4* w1v = (const float4*)w1s;
    const float4* bv  = (const float4*)bs;
    float4 acc[16];
#pragma unroll
    for (int j4 = 0; j4 < 16; j4++) acc[j4] = bv[j4];
    const float4* h1v = (const float4*)(h1 + (long)i * 32);
    float pr[32];
#pragma unroll
    for (int q = 0; q < 4; q++) {
        uint4 P = p1b[(long)i * 4 + q];
        pr[8 * q + 0] = blo(P.x); pr[8 * q + 1] = bhi(P.x);
        pr[8 * q + 2] = blo(P.y); pr[8 * q + 3] = bhi(P.y);
        pr[8 * q + 4] = blo(P.z); pr[8 * q + 5] = bhi(P.z);
        pr[8 * q + 6] = blo(P.w); pr[8 * q + 7] = bhi(P.w);
    }
#pragma unroll
    for (int k4 = 0; k4 < 8; k4++) {
        float4 a = h1v[k4];
        float av[4] = {a.x, a.y, a.z, a.w};
#pragma unroll
        for (int s = 0; s < 4; s++) {
            int k = k4 * 4 + s;
            float aa = av[s], pp = pr[k];
#pragma unroll
            for (int j4 = 0; j4 < 16; j4++) {
                float4 w0r = w0v[k * 16 + j4];
                float4 w1r = w1v[k * 16 + j4];
                acc[j4].x += aa * w0r.x + pp * w1r.x;
                acc[j4].y += aa * w0r.y + pp * w1r.y;
                acc[j4].z += aa * w0r.z + pp * w1r.z;
                acc[j4].w += aa * w0r.w + pp * w1r.w;
            }
        }
    }
    float4* out = (float4*)(h2 + (long)i * 64);
#pragma unroll
    for (int j4 = 0; j4 < 16; j4++) {
        float4 v = acc[j4];
        v.x = v.x > 0.f ? v.x : v.x * NEG_SLOPE;
        v.y = v.y > 0.f ? v.y : v.y * NEG_SLOPE;
        v.z = v.z > 0.f ? v.z : v.z * NEG_SLOPE;
        v.w = v.w > 0.f ? v.w : v.w * NEG_SLOPE;
        out[j4] = v;
    }
}

// ---- fused pooled sums over h2 ------------------------------------------
// sbuf[j]    += sum_i h2[i][j]
// sbuf[64+j] += sum_i (presum[i]*dinv[i]) * h2[i][j]   (cw = presum*dinv)
__global__ void sum2_kernel(const float* __restrict__ h2, const float* __restrict__ presum,
                            const float* __restrict__ dinv, float* __restrict__ sbuf, long total) {
    long tid = (long)blockIdx.x * blockDim.x + threadIdx.x;
    long stride = (long)gridDim.x * blockDim.x;   // multiple of 64
    float a1 = 0.f, a2 = 0.f;
    for (long idx = tid; idx < total; idx += stride) {
        float v = h2[idx];
        long i = idx >> 6;
        a1 += v;
        a2 += presum[i] * dinv[i] * v;
    }
    __shared__ float red1[256];
    __shared__ float red2[256];
    red1[threadIdx.x] = a1;
    red2[threadIdx.x] = a2;
    __syncthreads();
    if (threadIdx.x < 64) {
        float s1 = red1[threadIdx.x] + red1[threadIdx.x + 64] + red1[threadIdx.x + 128] + red1[threadIdx.x + 192];
        float s2 = red2[threadIdx.x] + red2[threadIdx.x + 64] + red2[threadIdx.x + 128] + red2[threadIdx.x + 192];
        atomAddF(&sbuf[threadIdx.x], s1);
        atomAddF(&sbuf[64 + threadIdx.x], s2);
    }
}

// ---- pooled = (s1/N)@w30 + (s2/N)@w31 + b3; out = log_softmax -----------
__global__ void final_kernel(const float* __restrict__ sbuf,
                             const float* __restrict__ w30, const float* __restrict__ w31,
                             const float* __restrict__ b3, float* __restrict__ out, float invN) {
    if (threadIdx.x != 0 || blockIdx.x != 0) return;
    const float* s1 = sbuf;
    const float* s2 = sbuf + 64;
    float p[2];
    for (int c = 0; c < 2; c++) {
        float a = 0.f;
        for (int k = 0; k < 64; k++) a += s1[k] * w30[k * 2 + c] + s2[k] * w31[k * 2 + c];
        p[c] = a * invN + b3[c];
    }
    float m = fmaxf(p[0], p[1]);
    float lse = m + logf(expf(p[0] - m) + expf(p[1] - m));
    out[0] = p[0] - lse;
    out[1] = p[1] - lse;
}

extern "C" void kernel_launch(void* const* d_in, const int* in_sizes, int n_in,
                              void* d_out, int out_size, void* d_ws, size_t ws_size,
                              hipStream_t stream) {
    const float* x    = (const float*)d_in[0];
    const int*   ei   = (const int*)d_in[1];
    const float* attr = (const float*)d_in[2];
    const float* w1_0 = (const float*)d_in[3];
    const float* b1   = (const float*)d_in[4];
    const float* w2_0 = (const float*)d_in[5];
    const float* w2_1 = (const float*)d_in[6];
    const float* b2   = (const float*)d_in[7];
    const float* w3_0 = (const float*)d_in[8];
    const float* w3_1 = (const float*)d_in[9];
    const float* b3   = (const float*)d_in[10];

    const int N = in_sizes[0] / 20;   // 100000
    const int E = in_sizes[2];        // 3200000
    const int* row = ei;
    const int* col = ei + E;
    const int NB = (N + 255) >> 8;    // 391 buckets (<= 512)

    // workspace layout (words)
    long big = (long)(2L * E > 64L * N ? 2L * E : 64L * N);
    float* ws = (float*)d_ws;
    float* dinv     = ws;                          // N
    float* presum   = ws + N;                      // N
    int*   rowptr   = (int*)(ws + 2L * N);         // N+1 (alloc N+4)
    int*   bhist_p  = (int*)(ws + 3L * N + 4);     // 512*PAD
    int*   bbase    = (int*)(ws + 3L * N + 4 + 512L * PAD);          // 513 (alloc 516)
    int*   bcursor_p= (int*)(ws + 3L * N + 520 + 512L * PAD);        // 512*PAD
    float* sbuf     = ws + 3L * N + 520 + 1024L * PAD;               // 128
    long   offA     = (3L * N + 648 + 1024L * PAD + 15) & ~15L;      // 64B-align regA
    float* regA     = ws + offA;                        // big: staging, then h1+p1b+h1b
    float* regB     = regA + big;                       // big: sorted, then h2

    int2*  staging = (int2*)regA;               // dead after finalize
    float* h1      = regA;                      // fp32, 32N words (overlays staging)
    uint4* p1b     = (uint4*)(regA + 32L * N);  // bf16, 16N words
    uint4* h1b     = (uint4*)(regA + 48L * N);  // bf16 (dinv-scaled), 16N words
    int2*  sorted  = (int2*)regB;               // dead after gather
    float* h2      = regB;                      // overlays sorted

    // zero accumulated regions (ws is poisoned before every launch)
    hipMemsetAsync(bhist_p, 0, 512 * PAD * 4, stream);
    hipMemsetAsync(presum, 0, (size_t)N * 4, stream);
    hipMemsetAsync(sbuf, 0, 128 * 4, stream);

    const int B = 256;
    const int NCH = (E + CH - 1) / CH;   // chunk-blocks for hist/scatter
    bucket_hist_kernel<<<NCH, B, 0, stream>>>(row, bhist_p, E, NB);
    bucket_scan_kernel<<<1, 512, 0, stream>>>(bhist_p, bbase, bcursor_p, rowptr, NB, N, E);
    bucket_scatter_kernel<<<NCH, B, 0, stream>>>(row, col, attr, bcursor_p, staging, E, NB);
    bucket_finalize_kernel<<<NB, 256, 0, stream>>>(bbase, staging, sorted, rowptr, dinv, N);
    h1_kernel<<<(N + B - 1) / B, B, 0, stream>>>(x, w1_0, b1, dinv, h1, h1b, N);
    {
        long t = (long)N * 4;
        gather_kernel<<<(int)((t + B - 1) / B), B, 0, stream>>>(rowptr, sorted, h1b, p1b, presum, N);
    }
    h2_kernel<<<(N + B - 1) / B, B, 0, stream>>>(h1, p1b, w2_0, w2_1, b2, h2, N);
    sum2_kernel<<<256, B, 0, stream>>>(h2, presum, dinv, sbuf, (long)N * 64);
    final_kernel<<<1, 64, 0, stream>>>(sbuf, w3_0, w3_1, b3, (float*)d_out, 1.0f / (float)N);
}

// Round 3
// 515.196 us; speedup vs baseline: 1.0520x; 1.0432x over previous
//
#include <hip/hip_runtime.h>
#include <hip/hip_bf16.h>

#define NEG_SLOPE 0.01f
#define CH 4096            // edges per block in hist/scatter (LDS-aggregated)
#define PAD 16             // 64B stride for contended global counters
// Dual bucket sort: row-bucketed CSR for the gather, col-bucketed staging for
// the presum (cw) aggregation -> NO per-edge global atomics anywhere.
// bucket id = id >> 8 (256 ids per bucket); NB = ceil(N/256) <= 512.
// Packing: {other_id (<2^24) | low8(key_id) << 24}.
#define NT 16              // col tiles (col < 2^17 -> tile = col>>13 in [0,16))
#define TILE_SHIFT 13
#define KEYS (256 * NT)    // row-sort bins: (rowlow, tile)

__device__ __forceinline__ void atomAddF(float* p, float v) {
    unsafeAtomicAdd(p, v);
}

// bf16 pack/unpack (round-to-nearest-even; finite values only)
__device__ __forceinline__ unsigned bf16rn(float f) {
    unsigned u = __float_as_uint(f);
    return (u + 0x7FFFu + ((u >> 16) & 1u)) >> 16;
}
__device__ __forceinline__ unsigned pack2(float a, float b) {
    return bf16rn(a) | (bf16rn(b) << 16);
}
__device__ __forceinline__ float blo(unsigned u) { return __uint_as_float(u << 16); }
__device__ __forceinline__ float bhi(unsigned u) { return __uint_as_float(u & 0xFFFF0000u); }

// ---- phase 1: dual bucket histogram (row and col), block-aggregated -----
__global__ void hist2_kernel(const int* __restrict__ row, const int* __restrict__ col,
                             int* __restrict__ bhR, int* __restrict__ bhC, int E, int NB) {
    __shared__ int lhR[512];
    __shared__ int lhC[512];
    for (int t = threadIdx.x; t < 512; t += 256) { lhR[t] = 0; lhC[t] = 0; }
    __syncthreads();
    int base = blockIdx.x * CH;
    int end = min(base + CH, E);
    for (int e = base + threadIdx.x; e < end; e += 256) {
        atomicAdd(&lhR[row[e] >> 8], 1);
        atomicAdd(&lhC[col[e] >> 8], 1);
    }
    __syncthreads();
    for (int t = threadIdx.x; t < NB; t += 256) {
        if (lhR[t]) atomicAdd(&bhR[t * PAD], lhR[t]);
        if (lhC[t]) atomicAdd(&bhC[t * PAD], lhC[t]);
    }
}

// ---- phase 2: exclusive scan of bucket counts (NB <= 512), init cursors -
__global__ void bucket_scan_kernel(const int* __restrict__ bhist_p, int* __restrict__ bbase,
                                   int* __restrict__ bcursor_p, int* __restrict__ rowptr,
                                   int NB, int N, int E) {
    __shared__ int s[512];
    int t = threadIdx.x;
    int v = (t < NB) ? bhist_p[t * PAD] : 0;
    s[t] = v;
    __syncthreads();
    for (int off = 1; off < 512; off <<= 1) {
        int x = (t >= off) ? s[t - off] : 0;
        __syncthreads();
        s[t] += x;
        __syncthreads();
    }
    if (t < NB) { bbase[t] = s[t] - v; bcursor_p[t * PAD] = s[t] - v; }
    if (t == 0) { bbase[NB] = E; rowptr[N] = E; }
}

// ---- phase 3: dual block-aggregated scatter -----------------------------
// stagingR (row-bucketed): {col | rowlow<<24, attr}
// stagingC (col-bucketed): {row | collow<<24, attr}
__global__ void scatter2_kernel(const int* __restrict__ row, const int* __restrict__ col,
                                const float* __restrict__ attr,
                                int* __restrict__ bcurR, int* __restrict__ bcurC,
                                int2* __restrict__ stagingR, int2* __restrict__ stagingC,
                                int E, int NB) {
    __shared__ int lhR[512], lbR[512], lcR[512];
    __shared__ int lhC[512], lbC[512], lcC[512];
    for (int t = threadIdx.x; t < 512; t += 256) {
        lhR[t] = 0; lcR[t] = 0; lhC[t] = 0; lcC[t] = 0;
    }
    __syncthreads();
    int base = blockIdx.x * CH;
    int end = min(base + CH, E);
    for (int e = base + threadIdx.x; e < end; e += 256) {
        atomicAdd(&lhR[row[e] >> 8], 1);
        atomicAdd(&lhC[col[e] >> 8], 1);
    }
    __syncthreads();
    for (int t = threadIdx.x; t < NB; t += 256) {
        if (lhR[t]) lbR[t] = atomicAdd(&bcurR[t * PAD], lhR[t]);
        if (lhC[t]) lbC[t] = atomicAdd(&bcurC[t * PAD], lhC[t]);
    }
    __syncthreads();
    for (int e = base + threadIdx.x; e < end; e += 256) {
        int r = row[e], c = col[e];
        int ab = __float_as_int(attr[e]);
        int posR = lbR[r >> 8] + atomicAdd(&lcR[r >> 8], 1);
        stagingR[posR] = make_int2(c | ((r & 255) << 24), ab);
        int posC = lbC[c >> 8] + atomicAdd(&lcC[c >> 8], 1);
        stagingC[posC] = make_int2(r | ((c & 255) << 24), ab);
    }
}

// ---- phase 4a: per-row-bucket degree -> rowptr, dinv --------------------
__global__ void rowdeg_kernel(const int* __restrict__ bbaseR, const int2* __restrict__ stagingR,
                              int* __restrict__ rowptr, float* __restrict__ dinv, int N) {
    __shared__ int lcount[256];
    __shared__ int lscan[256];
    __shared__ float ldeg[256];
    int t = threadIdx.x;
    int b = blockIdx.x;
    int base = bbaseR[b], end = bbaseR[b + 1];
    lcount[t] = 0;
    ldeg[t] = 0.f;
    __syncthreads();
    for (int e = base + t; e < end; e += 256) {
        int2 w = stagingR[e];
        int rl = (w.x >> 24) & 255;
        atomicAdd(&lcount[rl], 1);
        atomicAdd(&ldeg[rl], __int_as_float(w.y));
    }
    __syncthreads();
    lscan[t] = lcount[t];
    __syncthreads();
    for (int off = 1; off < 256; off <<= 1) {
        int x = (t >= off) ? lscan[t - off] : 0;
        __syncthreads();
        lscan[t] += x;
        __syncthreads();
    }
    int excl = lscan[t] - lcount[t];
    int grow = (b << 8) + t;
    if (grow < N) {
        float d = ldeg[t];
        rowptr[grow] = base + excl;
        dinv[grow] = d > 0.f ? rsqrtf(d) : 0.f;
    }
}

// ---- phase 4b: per-col-bucket presum (NO global atomics) ----------------
// presum[c] = sum_{e: col=c} -dinv[row_e] * attr_e
__global__ void col_finalize_kernel(const int* __restrict__ bbaseC,
                                    const int2* __restrict__ stagingC,
                                    const float* __restrict__ dinv,
                                    float* __restrict__ presum, int N) {
    __shared__ float bins[256];
    int t = threadIdx.x;
    int b = blockIdx.x;
    int base = bbaseC[b], end = bbaseC[b + 1];
    bins[t] = 0.f;
    __syncthreads();
    for (int e = base + t; e < end; e += 256) {
        int2 w = stagingC[e];
        int r = w.x & 0xFFFFFF;
        int cl = (w.x >> 24) & 255;
        float pre = -dinv[r] * __int_as_float(w.y);
        atomicAdd(&bins[cl], pre);   // LDS float atomic
    }
    __syncthreads();
    int grow = (b << 8) + t;
    if (grow < N) presum[grow] = bins[t];
}

// ---- phase 4c: per-row-bucket counting sort -> sorted CSR ---------------
// key = (rowlow, col>>13): CSR intact, rows tile-ordered for gather locality.
// sorted.y = pre = -dinv[row] * attr   (dinv[col] is baked into h1b)
__global__ void rowsort_kernel(const int* __restrict__ bbaseR, const int2* __restrict__ stagingR,
                               const float* __restrict__ dinv,
                               int2* __restrict__ sorted, int N) {
    __shared__ int lcount[KEYS];
    __shared__ int lsum[256];
    __shared__ float sdinv[256];
    int t = threadIdx.x;
    int b = blockIdx.x;
    int base = bbaseR[b], end = bbaseR[b + 1];
    for (int k = t; k < KEYS; k += 256) lcount[k] = 0;
    int grow = (b << 8) + t;
    sdinv[t] = (grow < N) ? dinv[grow] : 0.f;
    __syncthreads();
    for (int e = base + t; e < end; e += 256) {
        int2 w = stagingR[e];
        int rl = (w.x >> 24) & 255;
        int tile = (w.x & 0xFFFFFF) >> TILE_SHIFT;
        atomicAdd(&lcount[rl * NT + tile], 1);
    }
    __syncthreads();
    int vals[NT];
    int s = 0;
#pragma unroll
    for (int j = 0; j < NT; j++) { vals[j] = s; s += lcount[t * NT + j]; }
    lsum[t] = s;
    __syncthreads();
    for (int off = 1; off < 256; off <<= 1) {
        int x = (t >= off) ? lsum[t - off] : 0;
        __syncthreads();
        lsum[t] += x;
        __syncthreads();
    }
    int rowexcl = lsum[t] - s;
#pragma unroll
    for (int j = 0; j < NT; j++) lcount[t * NT + j] = rowexcl + vals[j];  // -> cursors
    __syncthreads();
    for (int e = base + t; e < end; e += 256) {
        int2 w = stagingR[e];
        int rl = (w.x >> 24) & 255;
        int c = w.x & 0xFFFFFF;
        int key = rl * NT + (c >> TILE_SHIFT);
        int pos = base + atomicAdd(&lcount[key], 1);
        float pre = -sdinv[rl] * __int_as_float(w.y);
        sorted[pos] = make_int2(c, __float_as_int(pre));   // {col, pre}
    }
}

// ---- h1 = leaky_relu(x @ w1 + b1); also h1b = bf16(dinv[i] * h1) --------
// h1b row = 32 bf16 = 64B = 4 uint4; feature 2k low half, 2k+1 high half.
__global__ void h1_kernel(const float* __restrict__ x, const float* __restrict__ w,
                          const float* __restrict__ b, const float* __restrict__ dinv,
                          float* __restrict__ h1, uint4* __restrict__ h1b, int N) {
    __shared__ float ws[20 * 32];
    __shared__ float bs[32];
    for (int t = threadIdx.x; t < 640; t += blockDim.x) ws[t] = w[t];
    if (threadIdx.x < 32) bs[threadIdx.x] = b[threadIdx.x];
    __syncthreads();
    int i = blockIdx.x * blockDim.x + threadIdx.x;
    if (i >= N) return;
    float xi[20];
#pragma unroll
    for (int k = 0; k < 20; k++) xi[k] = x[i * 20 + k];
    float acc[32];
#pragma unroll
    for (int j = 0; j < 32; j++) acc[j] = bs[j];
#pragma unroll
    for (int k = 0; k < 20; k++) {
        float a = xi[k];
#pragma unroll
        for (int j = 0; j < 32; j++) acc[j] += a * ws[k * 32 + j];
    }
#pragma unroll
    for (int j = 0; j < 32; j++) {
        float v = acc[j];
        acc[j] = v > 0.f ? v : v * NEG_SLOPE;
    }
    float4* h1v = (float4*)(h1 + (long)i * 32);
#pragma unroll
    for (int j4 = 0; j4 < 8; j4++)
        h1v[j4] = make_float4(acc[j4 * 4], acc[j4 * 4 + 1], acc[j4 * 4 + 2], acc[j4 * 4 + 3]);
    float di = dinv[i];
    unsigned u[16];
#pragma unroll
    for (int k = 0; k < 16; k++) u[k] = pack2(di * acc[2 * k], di * acc[2 * k + 1]);
#pragma unroll
    for (int q = 0; q < 4; q++)
        h1b[(long)i * 4 + q] = make_uint4(u[4 * q], u[4 * q + 1], u[4 * q + 2], u[4 * q + 3]);
}

// ---- pure gather-propagate (no atomics) ---------------------------------
// p1[i] = sum_{e in CSR row i} pre_e * h1b[col_e]   (dinv[col] baked into h1b)
// 4 threads per node, each owning 8 bf16 features (one uint4 = 64B/row total).
__global__ void gather_kernel(const int* __restrict__ rowptr, const int2* __restrict__ sorted,
                              const uint4* __restrict__ h1b, uint4* __restrict__ p1b, int N) {
    long idx = (long)blockIdx.x * blockDim.x + threadIdx.x;
    int node = (int)(idx >> 2);
    int part = (int)(idx & 3);
    if (node >= N) return;
    int s0 = rowptr[node], s1 = rowptr[node + 1];
    float acc[8];
#pragma unroll
    for (int k = 0; k < 8; k++) acc[k] = 0.f;
    int e = s0;
    for (; e + 4 <= s1; e += 4) {
        int2 q0 = sorted[e], q1 = sorted[e + 1], q2 = sorted[e + 2], q3 = sorted[e + 3];
        float n0 = __int_as_float(q0.y), n1 = __int_as_float(q1.y);
        float n2 = __int_as_float(q2.y), n3 = __int_as_float(q3.y);
        uint4 v0 = h1b[(long)q0.x * 4 + part];
        uint4 v1 = h1b[(long)q1.x * 4 + part];
        uint4 v2 = h1b[(long)q2.x * 4 + part];
        uint4 v3 = h1b[(long)q3.x * 4 + part];
        acc[0] += n0 * blo(v0.x) + n1 * blo(v1.x) + n2 * blo(v2.x) + n3 * blo(v3.x);
        acc[1] += n0 * bhi(v0.x) + n1 * bhi(v1.x) + n2 * bhi(v2.x) + n3 * bhi(v3.x);
        acc[2] += n0 * blo(v0.y) + n1 * blo(v1.y) + n2 * blo(v2.y) + n3 * blo(v3.y);
        acc[3] += n0 * bhi(v0.y) + n1 * bhi(v1.y) + n2 * bhi(v2.y) + n3 * bhi(v3.y);
        acc[4] += n0 * blo(v0.z) + n1 * blo(v1.z) + n2 * blo(v2.z) + n3 * blo(v3.z);
        acc[5] += n0 * bhi(v0.z) + n1 * bhi(v1.z) + n2 * bhi(v2.z) + n3 * bhi(v3.z);
        acc[6] += n0 * blo(v0.w) + n1 * blo(v1.w) + n2 * blo(v2.w) + n3 * blo(v3.w);
        acc[7] += n0 * bhi(v0.w) + n1 * bhi(v1.w) + n2 * bhi(v2.w) + n3 * bhi(v3.w);
    }
    for (; e < s1; e++) {
        int2 q = sorted[e];
        float nm = __int_as_float(q.y);
        uint4 v = h1b[(long)q.x * 4 + part];
        acc[0] += nm * blo(v.x); acc[1] += nm * bhi(v.x);
        acc[2] += nm * blo(v.y); acc[3] += nm * bhi(v.y);
        acc[4] += nm * blo(v.z); acc[5] += nm * bhi(v.z);
        acc[6] += nm * blo(v.w); acc[7] += nm * bhi(v.w);
    }
    p1b[(long)node * 4 + part] = make_uint4(pack2(acc[0], acc[1]), pack2(acc[2], acc[3]),
                                            pack2(acc[4], acc[5]), pack2(acc[6], acc[7]));
}

// ---- h2 = leaky_relu(h1 @ w2_0 + p1 @ w2_1 + b2), 32 -> 64 --------------
// h1 fp32, p1 bf16-packed (same layout as h1b).
__global__ void __launch_bounds__(256, 1)
h2_kernel(const float* __restrict__ h1, const uint4* __restrict__ p1b,
          const float* __restrict__ w0, const float* __restrict__ w1,
          const float* __restrict__ b, float* __restrict__ h2, int N) {
    __shared__ float w0s[32 * 64];
    __shared__ float w1s[32 * 64];
    __shared__ float bs[64];
    for (int t = threadIdx.x; t < 2048; t += blockDim.x) { w0s[t] = w0[t]; w1s[t] = w1[t]; }
    if (threadIdx.x < 64) bs[threadIdx.x] = b[threadIdx.x];
    __syncthreads();
    int i = blockIdx.x * blockDim.x + threadIdx.x;
    if (i >= N) return;
    const float4* w0v = (const float4*)w0s;   // [k*16 + j4]
    const float4* w1v = (const float4*)w1s;
    const float4* bv  = (const float4*)bs;
    float4 acc[16];
#pragma unroll
    for (int j4 = 0; j4 < 16; j4++) acc[j4] = bv[j4];
    const float4* h1v = (const float4*)(h1 + (long)i * 32);
    float pr[32];
#pragma unroll
    for (int q = 0; q < 4; q++) {
        uint4 P = p1b[(long)i * 4 + q];
        pr[8 * q + 0] = blo(P.x); pr[8 * q + 1] = bhi(P.x);
        pr[8 * q + 2] = blo(P.y); pr[8 * q + 3] = bhi(P.y);
        pr[8 * q + 4] = blo(P.z); pr[8 * q + 5] = bhi(P.z);
        pr[8 * q + 6] = blo(P.w); pr[8 * q + 7] = bhi(P.w);
    }
#pragma unroll
    for (int k4 = 0; k4 < 8; k4++) {
        float4 a = h1v[k4];
        float av[4] = {a.x, a.y, a.z, a.w};
#pragma unroll
        for (int s = 0; s < 4; s++) {
            int k = k4 * 4 + s;
            float aa = av[s], pp = pr[k];
#pragma unroll
            for (int j4 = 0; j4 < 16; j4++) {
                float4 w0r = w0v[k * 16 + j4];
                float4 w1r = w1v[k * 16 + j4];
                acc[j4].x += aa * w0r.x + pp * w1r.x;
                acc[j4].y += aa * w0r.y + pp * w1r.y;
                acc[j4].z += aa * w0r.z + pp * w1r.z;
                acc[j4].w += aa * w0r.w + pp * w1r.w;
            }
        }
    }
    float4* out = (float4*)(h2 + (long)i * 64);
#pragma unroll
    for (int j4 = 0; j4 < 16; j4++) {
        float4 v = acc[j4];
        v.x = v.x > 0.f ? v.x : v.x * NEG_SLOPE;
        v.y = v.y > 0.f ? v.y : v.y * NEG_SLOPE;
        v.z = v.z > 0.f ? v.z : v.z * NEG_SLOPE;
        v.w = v.w > 0.f ? v.w : v.w * NEG_SLOPE;
        out[j4] = v;
    }
}

// ---- fused pooled sums over h2 ------------------------------------------
// sbuf[j]    += sum_i h2[i][j]
// sbuf[64+j] += sum_i (presum[i]*dinv[i]) * h2[i][j]   (cw = presum*dinv)
__global__ void sum2_kernel(const float* __restrict__ h2, const float* __restrict__ presum,
                            const float* __restrict__ dinv, float* __restrict__ sbuf, long total) {
    long tid = (long)blockIdx.x * blockDim.x + threadIdx.x;
    long stride = (long)gridDim.x * blockDim.x;   // multiple of 64
    float a1 = 0.f, a2 = 0.f;
    for (long idx = tid; idx < total; idx += stride) {
        float v = h2[idx];
        long i = idx >> 6;
        a1 += v;
        a2 += presum[i] * dinv[i] * v;
    }
    __shared__ float red1[256];
    __shared__ float red2[256];
    red1[threadIdx.x] = a1;
    red2[threadIdx.x] = a2;
    __syncthreads();
    if (threadIdx.x < 64) {
        float s1 = red1[threadIdx.x] + red1[threadIdx.x + 64] + red1[threadIdx.x + 128] + red1[threadIdx.x + 192];
        float s2 = red2[threadIdx.x] + red2[threadIdx.x + 64] + red2[threadIdx.x + 128] + red2[threadIdx.x + 192];
        atomAddF(&sbuf[threadIdx.x], s1);
        atomAddF(&sbuf[64 + threadIdx.x], s2);
    }
}

// ---- pooled = (s1/N)@w30 + (s2/N)@w31 + b3; out = log_softmax -----------
__global__ void final_kernel(const float* __restrict__ sbuf,
                             const float* __restrict__ w30, const float* __restrict__ w31,
                             const float* __restrict__ b3, float* __restrict__ out, float invN) {
    if (threadIdx.x != 0 || blockIdx.x != 0) return;
    const float* s1 = sbuf;
    const float* s2 = sbuf + 64;
    float p[2];
    for (int c = 0; c < 2; c++) {
        float a = 0.f;
        for (int k = 0; k < 64; k++) a += s1[k] * w30[k * 2 + c] + s2[k] * w31[k * 2 + c];
        p[c] = a * invN + b3[c];
    }
    float m = fmaxf(p[0], p[1]);
    float lse = m + logf(expf(p[0] - m) + expf(p[1] - m));
    out[0] = p[0] - lse;
    out[1] = p[1] - lse;
}

extern "C" void kernel_launch(void* const* d_in, const int* in_sizes, int n_in,
                              void* d_out, int out_size, void* d_ws, size_t ws_size,
                              hipStream_t stream) {
    const float* x    = (const float*)d_in[0];
    const int*   ei   = (const int*)d_in[1];
    const float* attr = (const float*)d_in[2];
    const float* w1_0 = (const float*)d_in[3];
    const float* b1   = (const float*)d_in[4];
    const float* w2_0 = (const float*)d_in[5];
    const float* w2_1 = (const float*)d_in[6];
    const float* b2   = (const float*)d_in[7];
    const float* w3_0 = (const float*)d_in[8];
    const float* w3_1 = (const float*)d_in[9];
    const float* b3   = (const float*)d_in[10];

    const int N = in_sizes[0] / 20;   // 100000
    const int E = in_sizes[2];        // 3200000
    const int* row = ei;
    const int* col = ei + E;
    const int NB = (N + 255) >> 8;    // 391 buckets (<= 512)

    // workspace layout (words)
    long big = (long)(2L * E > 64L * N ? 2L * E : 64L * N);
    float* ws = (float*)d_ws;
    float* dinv   = ws;                            // N
    float* presum = ws + N;                        // N
    int*   rowptr = (int*)(ws + 2L * N);           // N+1 (alloc N+4)
    long   off    = 3L * N + 4;
    int*   bhR    = (int*)(ws + off); off += 512L * PAD;   // row hist (padded)
    int*   bhC    = (int*)(ws + off); off += 512L * PAD;   // col hist (padded)
    int*   bbaseR = (int*)(ws + off); off += 516;
    int*   bbaseC = (int*)(ws + off); off += 516;
    int*   bcurR  = (int*)(ws + off); off += 512L * PAD;
    int*   bcurC  = (int*)(ws + off); off += 512L * PAD;
    float* sbuf   = ws + off;         off += 128;
    long   offA   = (off + 15) & ~15L;                     // 64B-align regA
    float* regA   = ws + offA;                  // big: stagingR, then h1+p1b+h1b
    float* regB   = regA + big;                 // big: stagingC, then sorted, then h2

    int2*  stagingR = (int2*)regA;              // dead after rowsort (4c)
    float* h1       = regA;                     // fp32, 32N words
    uint4* p1b      = (uint4*)(regA + 32L * N); // bf16, 16N words
    uint4* h1b      = (uint4*)(regA + 48L * N); // bf16 (dinv-scaled), 16N words
    int2*  stagingC = (int2*)regB;              // dead after col_finalize (4b)
    int2*  sorted   = (int2*)regB;              // written in 4c, dead after gather
    float* h2       = regB;                     // overlays sorted after gather

    // zero accumulated regions (ws is poisoned before every launch)
    hipMemsetAsync(bhR, 0, 2 * 512 * PAD * 4, stream);   // bhR + bhC contiguous
    hipMemsetAsync(sbuf, 0, 128 * 4, stream);

    const int B = 256;
    const int NCH = (E + CH - 1) / CH;   // chunk-blocks for hist/scatter
    hist2_kernel<<<NCH, B, 0, stream>>>(row, col, bhR, bhC, E, NB);
    bucket_scan_kernel<<<1, 512, 0, stream>>>(bhR, bbaseR, bcurR, rowptr, NB, N, E);
    bucket_scan_kernel<<<1, 512, 0, stream>>>(bhC, bbaseC, bcurC, rowptr, NB, N, E);
    scatter2_kernel<<<NCH, B, 0, stream>>>(row, col, attr, bcurR, bcurC, stagingR, stagingC, E, NB);
    rowdeg_kernel<<<NB, 256, 0, stream>>>(bbaseR, stagingR, rowptr, dinv, N);
    col_finalize_kernel<<<NB, 256, 0, stream>>>(bbaseC, stagingC, dinv, presum, N);
    rowsort_kernel<<<NB, 256, 0, stream>>>(bbaseR, stagingR, dinv, sorted, N);
    h1_kernel<<<(N + B - 1) / B, B, 0, stream>>>(x, w1_0, b1, dinv, h1, h1b, N);
    {
        long t = (long)N * 4;
        gather_kernel<<<(int)((t + B - 1) / B), B, 0, stream>>>(rowptr, sorted, h1b, p1b, N);
    }
    h2_kernel<<<(N + B - 1) / B, B, 0, stream>>>(h1, p1b, w2_0, w2_1, b2, h2, N);
    sum2_kernel<<<256, B, 0, stream>>>(h2, presum, dinv, sbuf, (long)N * 64);
    final_kernel<<<1, 64, 0, stream>>>(sbuf, w3_0, w3_1, b3, (float*)d_out, 1.0f / (float)N);
}

// Round 4
// 470.440 us; speedup vs baseline: 1.1521x; 1.0951x over previous
//
#include <hip/hip_runtime.h>
#include <hip/hip_bf16.h>

#define NEG_SLOPE 0.01f
#define CH 4096            // edges per block in hist/scatter (LDS-aggregated)
#define PAD 16             // 64B stride for contended global counters
// Dual bucket sort: row-bucketed CSR for the gather, col-bucketed staging for
// the presum (cw) aggregation -> NO per-edge global atomics anywhere.
// bucket id = id >> 8 (256 ids per bucket); NB = ceil(N/256) <= 512.
// Packing: {other_id (<2^24) | low8(key_id) << 24}.
// scatter2 does an in-block LDS counting sort so staging writes stream out as
// contiguous runs per bucket (fixes 4x write amplification: 8B scattered
// stores were each costing a 32B fabric burst).
#define NT 16              // col tiles (col < 2^17 -> tile = col>>13 in [0,16))
#define TILE_SHIFT 13
#define KEYS (256 * NT)    // row-sort bins: (rowlow, tile)

__device__ __forceinline__ void atomAddF(float* p, float v) {
    unsafeAtomicAdd(p, v);
}

// bf16 pack/unpack (round-to-nearest-even; finite values only)
__device__ __forceinline__ unsigned bf16rn(float f) {
    unsigned u = __float_as_uint(f);
    return (u + 0x7FFFu + ((u >> 16) & 1u)) >> 16;
}
__device__ __forceinline__ unsigned pack2(float a, float b) {
    return bf16rn(a) | (bf16rn(b) << 16);
}
__device__ __forceinline__ float blo(unsigned u) { return __uint_as_float(u << 16); }
__device__ __forceinline__ float bhi(unsigned u) { return __uint_as_float(u & 0xFFFF0000u); }

// ---- phase 1: dual bucket histogram (row and col), block-aggregated -----
__global__ void hist2_kernel(const int* __restrict__ row, const int* __restrict__ col,
                             int* __restrict__ bhR, int* __restrict__ bhC, int E, int NB) {
    __shared__ int lhR[512];
    __shared__ int lhC[512];
    for (int t = threadIdx.x; t < 512; t += 256) { lhR[t] = 0; lhC[t] = 0; }
    __syncthreads();
    int base = blockIdx.x * CH;
    int end = min(base + CH, E);
    for (int e = base + threadIdx.x; e < end; e += 256) {
        atomicAdd(&lhR[row[e] >> 8], 1);
        atomicAdd(&lhC[col[e] >> 8], 1);
    }
    __syncthreads();
    for (int t = threadIdx.x; t < NB; t += 256) {
        if (lhR[t]) atomicAdd(&bhR[t * PAD], lhR[t]);
        if (lhC[t]) atomicAdd(&bhC[t * PAD], lhC[t]);
    }
}

// ---- phase 2: exclusive scan of bucket counts (NB <= 512), init cursors -
__global__ void bucket_scan_kernel(const int* __restrict__ bhist_p, int* __restrict__ bbase,
                                   int* __restrict__ bcursor_p, int* __restrict__ rowptr,
                                   int NB, int N, int E) {
    __shared__ int s[512];
    int t = threadIdx.x;
    int v = (t < NB) ? bhist_p[t * PAD] : 0;
    s[t] = v;
    __syncthreads();
    for (int off = 1; off < 512; off <<= 1) {
        int x = (t >= off) ? s[t - off] : 0;
        __syncthreads();
        s[t] += x;
        __syncthreads();
    }
    if (t < NB) { bbase[t] = s[t] - v; bcursor_p[t * PAD] = s[t] - v; }
    if (t == 0) { bbase[NB] = E; rowptr[N] = E; }
}

// ---- phase 3: dual scatter with in-block LDS counting sort --------------
// stagingR (row-bucketed): {col | rowlow<<24, attr}
// stagingC (col-bucketed): {row | collow<<24, attr}
// Each side: hist -> reserve global runs -> local scan -> place into LDS
// grouped by bucket (+record dest) -> stream out coalesced.
__global__ void __launch_bounds__(256, 1)
scatter2_kernel(const int* __restrict__ row, const int* __restrict__ col,
                const float* __restrict__ attr,
                int* __restrict__ bcurR, int* __restrict__ bcurC,
                int2* __restrict__ stagingR, int2* __restrict__ stagingC,
                int E, int NB) {
    __shared__ int lh[512];
    __shared__ int lbase[512];
    __shared__ int loff[512];
    __shared__ int lcur[512];
    __shared__ int lscan[256];
    __shared__ int2 buf[CH];     // 32KB: block's edges grouped by bucket
    __shared__ int  dst[CH];     // 16KB: global destination per entry
    int t = threadIdx.x;
    int base = blockIdx.x * CH;
    int end = min(base + CH, E);
    int cnt = end - base;

    for (int side = 0; side < 2; side++) {
        const int* key   = side ? col : row;
        const int* other = side ? row : col;
        int* bcur        = side ? bcurC : bcurR;
        int2* out        = side ? stagingC : stagingR;
        // hist
        for (int k = t; k < 512; k += 256) { lh[k] = 0; lcur[k] = 0; }
        __syncthreads();
        for (int e = base + t; e < end; e += 256)
            atomicAdd(&lh[key[e] >> 8], 1);
        __syncthreads();
        // reserve global runs
        for (int k = t; k < NB; k += 256)
            if (lh[k]) lbase[k] = atomicAdd(&bcur[k * PAD], lh[k]);
        // local exclusive scan of lh[0..511] (pair per thread)
        int a0 = lh[2 * t], a1 = lh[2 * t + 1];
        int psum = a0 + a1;
        lscan[t] = psum;
        __syncthreads();
        for (int off = 1; off < 256; off <<= 1) {
            int x = (t >= off) ? lscan[t - off] : 0;
            __syncthreads();
            lscan[t] += x;
            __syncthreads();
        }
        int pexcl = lscan[t] - psum;
        loff[2 * t] = pexcl;
        loff[2 * t + 1] = pexcl + a0;
        __syncthreads();
        // place into LDS grouped by bucket
        for (int e = base + t; e < end; e += 256) {
            int k = key[e], o = other[e];
            int bk = k >> 8;
            int rank = atomicAdd(&lcur[bk], 1);
            int lpos = loff[bk] + rank;
            buf[lpos] = make_int2(o | ((k & 255) << 24), __float_as_int(attr[e]));
            dst[lpos] = lbase[bk] + rank;
        }
        __syncthreads();
        // coalesced write-out: consecutive j -> consecutive dst within runs
        for (int j = t; j < cnt; j += 256)
            out[dst[j]] = buf[j];
        __syncthreads();
    }
}

// ---- phase 4a: per-row-bucket degree -> rowptr, dinv --------------------
__global__ void rowdeg_kernel(const int* __restrict__ bbaseR, const int2* __restrict__ stagingR,
                              int* __restrict__ rowptr, float* __restrict__ dinv, int N) {
    __shared__ int lcount[256];
    __shared__ int lscan[256];
    __shared__ float ldeg[256];
    int t = threadIdx.x;
    int b = blockIdx.x;
    int base = bbaseR[b], end = bbaseR[b + 1];
    lcount[t] = 0;
    ldeg[t] = 0.f;
    __syncthreads();
    for (int e = base + t; e < end; e += 256) {
        int2 w = stagingR[e];
        int rl = (w.x >> 24) & 255;
        atomicAdd(&lcount[rl], 1);
        atomicAdd(&ldeg[rl], __int_as_float(w.y));
    }
    __syncthreads();
    lscan[t] = lcount[t];
    __syncthreads();
    for (int off = 1; off < 256; off <<= 1) {
        int x = (t >= off) ? lscan[t - off] : 0;
        __syncthreads();
        lscan[t] += x;
        __syncthreads();
    }
    int excl = lscan[t] - lcount[t];
    int grow = (b << 8) + t;
    if (grow < N) {
        float d = ldeg[t];
        rowptr[grow] = base + excl;
        dinv[grow] = d > 0.f ? rsqrtf(d) : 0.f;
    }
}

// ---- phase 4b: per-col-bucket presum (NO global atomics) ----------------
// presum[c] = sum_{e: col=c} -dinv[row_e] * attr_e
__global__ void col_finalize_kernel(const int* __restrict__ bbaseC,
                                    const int2* __restrict__ stagingC,
                                    const float* __restrict__ dinv,
                                    float* __restrict__ presum, int N) {
    __shared__ float bins[256];
    int t = threadIdx.x;
    int b = blockIdx.x;
    int base = bbaseC[b], end = bbaseC[b + 1];
    bins[t] = 0.f;
    __syncthreads();
    for (int e = base + t; e < end; e += 256) {
        int2 w = stagingC[e];
        int r = w.x & 0xFFFFFF;
        int cl = (w.x >> 24) & 255;
        float pre = -dinv[r] * __int_as_float(w.y);
        atomicAdd(&bins[cl], pre);   // LDS float atomic
    }
    __syncthreads();
    int grow = (b << 8) + t;
    if (grow < N) presum[grow] = bins[t];
}

// ---- phase 4c: per-row-bucket counting sort -> sorted CSR ---------------
// key = (rowlow, col>>13): CSR intact, rows tile-ordered for gather locality.
// sorted.y = pre = -dinv[row] * attr   (dinv[col] is baked into h1b)
__global__ void rowsort_kernel(const int* __restrict__ bbaseR, const int2* __restrict__ stagingR,
                               const float* __restrict__ dinv,
                               int2* __restrict__ sorted, int N) {
    __shared__ int lcount[KEYS];
    __shared__ int lsum[256];
    __shared__ float sdinv[256];
    int t = threadIdx.x;
    int b = blockIdx.x;
    int base = bbaseR[b], end = bbaseR[b + 1];
    for (int k = t; k < KEYS; k += 256) lcount[k] = 0;
    int grow = (b << 8) + t;
    sdinv[t] = (grow < N) ? dinv[grow] : 0.f;
    __syncthreads();
    for (int e = base + t; e < end; e += 256) {
        int2 w = stagingR[e];
        int rl = (w.x >> 24) & 255;
        int tile = (w.x & 0xFFFFFF) >> TILE_SHIFT;
        atomicAdd(&lcount[rl * NT + tile], 1);
    }
    __syncthreads();
    int vals[NT];
    int s = 0;
#pragma unroll
    for (int j = 0; j < NT; j++) { vals[j] = s; s += lcount[t * NT + j]; }
    lsum[t] = s;
    __syncthreads();
    for (int off = 1; off < 256; off <<= 1) {
        int x = (t >= off) ? lsum[t - off] : 0;
        __syncthreads();
        lsum[t] += x;
        __syncthreads();
    }
    int rowexcl = lsum[t] - s;
#pragma unroll
    for (int j = 0; j < NT; j++) lcount[t * NT + j] = rowexcl + vals[j];  // -> cursors
    __syncthreads();
    for (int e = base + t; e < end; e += 256) {
        int2 w = stagingR[e];
        int rl = (w.x >> 24) & 255;
        int c = w.x & 0xFFFFFF;
        int key = rl * NT + (c >> TILE_SHIFT);
        int pos = base + atomicAdd(&lcount[key], 1);
        float pre = -sdinv[rl] * __int_as_float(w.y);
        sorted[pos] = make_int2(c, __float_as_int(pre));   // {col, pre}
    }
}

// ---- h1 = leaky_relu(x @ w1 + b1); also h1b = bf16(dinv[i] * h1) --------
// h1b row = 32 bf16 = 64B = 4 uint4; feature 2k low half, 2k+1 high half.
__global__ void h1_kernel(const float* __restrict__ x, const float* __restrict__ w,
                          const float* __restrict__ b, const float* __restrict__ dinv,
                          float* __restrict__ h1, uint4* __restrict__ h1b, int N) {
    __shared__ float ws[20 * 32];
    __shared__ float bs[32];
    for (int t = threadIdx.x; t < 640; t += blockDim.x) ws[t] = w[t];
    if (threadIdx.x < 32) bs[threadIdx.x] = b[threadIdx.x];
    __syncthreads();
    int i = blockIdx.x * blockDim.x + threadIdx.x;
    if (i >= N) return;
    float xi[20];
#pragma unroll
    for (int k = 0; k < 20; k++) xi[k] = x[i * 20 + k];
    float acc[32];
#pragma unroll
    for (int j = 0; j < 32; j++) acc[j] = bs[j];
#pragma unroll
    for (int k = 0; k < 20; k++) {
        float a = xi[k];
#pragma unroll
        for (int j = 0; j < 32; j++) acc[j] += a * ws[k * 32 + j];
    }
#pragma unroll
    for (int j = 0; j < 32; j++) {
        float v = acc[j];
        acc[j] = v > 0.f ? v : v * NEG_SLOPE;
    }
    float4* h1v = (float4*)(h1 + (long)i * 32);
#pragma unroll
    for (int j4 = 0; j4 < 8; j4++)
        h1v[j4] = make_float4(acc[j4 * 4], acc[j4 * 4 + 1], acc[j4 * 4 + 2], acc[j4 * 4 + 3]);
    float di = dinv[i];
    unsigned u[16];
#pragma unroll
    for (int k = 0; k < 16; k++) u[k] = pack2(di * acc[2 * k], di * acc[2 * k + 1]);
#pragma unroll
    for (int q = 0; q < 4; q++)
        h1b[(long)i * 4 + q] = make_uint4(u[4 * q], u[4 * q + 1], u[4 * q + 2], u[4 * q + 3]);
}

// ---- pure gather-propagate (no atomics) ---------------------------------
// p1[i] = sum_{e in CSR row i} pre_e * h1b[col_e]   (dinv[col] baked into h1b)
// 4 threads per node, each owning 8 bf16 features (one uint4 = 64B/row total).
__global__ void gather_kernel(const int* __restrict__ rowptr, const int2* __restrict__ sorted,
                              const uint4* __restrict__ h1b, uint4* __restrict__ p1b, int N) {
    long idx = (long)blockIdx.x * blockDim.x + threadIdx.x;
    int node = (int)(idx >> 2);
    int part = (int)(idx & 3);
    if (node >= N) return;
    int s0 = rowptr[node], s1 = rowptr[node + 1];
    float acc[8];
#pragma unroll
    for (int k = 0; k < 8; k++) acc[k] = 0.f;
    int e = s0;
    for (; e + 4 <= s1; e += 4) {
        int2 q0 = sorted[e], q1 = sorted[e + 1], q2 = sorted[e + 2], q3 = sorted[e + 3];
        float n0 = __int_as_float(q0.y), n1 = __int_as_float(q1.y);
        float n2 = __int_as_float(q2.y), n3 = __int_as_float(q3.y);
        uint4 v0 = h1b[(long)q0.x * 4 + part];
        uint4 v1 = h1b[(long)q1.x * 4 + part];
        uint4 v2 = h1b[(long)q2.x * 4 + part];
        uint4 v3 = h1b[(long)q3.x * 4 + part];
        acc[0] += n0 * blo(v0.x) + n1 * blo(v1.x) + n2 * blo(v2.x) + n3 * blo(v3.x);
        acc[1] += n0 * bhi(v0.x) + n1 * bhi(v1.x) + n2 * bhi(v2.x) + n3 * bhi(v3.x);
        acc[2] += n0 * blo(v0.y) + n1 * blo(v1.y) + n2 * blo(v2.y) + n3 * blo(v3.y);
        acc[3] += n0 * bhi(v0.y) + n1 * bhi(v1.y) + n2 * bhi(v2.y) + n3 * bhi(v3.y);
        acc[4] += n0 * blo(v0.z) + n1 * blo(v1.z) + n2 * blo(v2.z) + n3 * blo(v3.z);
        acc[5] += n0 * bhi(v0.z) + n1 * bhi(v1.z) + n2 * bhi(v2.z) + n3 * bhi(v3.z);
        acc[6] += n0 * blo(v0.w) + n1 * blo(v1.w) + n2 * blo(v2.w) + n3 * blo(v3.w);
        acc[7] += n0 * bhi(v0.w) + n1 * bhi(v1.w) + n2 * bhi(v2.w) + n3 * bhi(v3.w);
    }
    for (; e < s1; e++) {
        int2 q = sorted[e];
        float nm = __int_as_float(q.y);
        uint4 v = h1b[(long)q.x * 4 + part];
        acc[0] += nm * blo(v.x); acc[1] += nm * bhi(v.x);
        acc[2] += nm * blo(v.y); acc[3] += nm * bhi(v.y);
        acc[4] += nm * blo(v.z); acc[5] += nm * bhi(v.z);
        acc[6] += nm * blo(v.w); acc[7] += nm * bhi(v.w);
    }
    p1b[(long)node * 4 + part] = make_uint4(pack2(acc[0], acc[1]), pack2(acc[2], acc[3]),
                                            pack2(acc[4], acc[5]), pack2(acc[6], acc[7]));
}

// ---- h2 = leaky_relu(h1 @ w2_0 + p1 @ w2_1 + b2), 32 -> 64 --------------
// h1 fp32, p1 bf16-packed (same layout as h1b).
__global__ void __launch_bounds__(256, 1)
h2_kernel(const float* __restrict__ h1, const uint4* __restrict__ p1b,
          const float* __restrict__ w0, const float* __restrict__ w1,
          const float* __restrict__ b, float* __restrict__ h2, int N) {
    __shared__ float w0s[32 * 64];
    __shared__ float w1s[32 * 64];
    __shared__ float bs[64];
    for (int t = threadIdx.x; t < 2048; t += blockDim.x) { w0s[t] = w0[t]; w1s[t] = w1[t]; }
    if (threadIdx.x < 64) bs[threadIdx.x] = b[threadIdx.x];
    __syncthreads();
    int i = blockIdx.x * blockDim.x + threadIdx.x;
    if (i >= N) return;
    const float4* w0v = (const float4*)w0s;   // [k*16 + j4]
    const float4* w1v = (const float4*)w1s;
    const float4* bv  = (const float4*)bs;
    float4 acc[16];
#pragma unroll
    for (int j4 = 0; j4 < 16; j4++) acc[j4] = bv[j4];
    const float4* h1v = (const float4*)(h1 + (long)i * 32);
    float pr[32];
#pragma unroll
    for (int q = 0; q < 4; q++) {
        uint4 P = p1b[(long)i * 4 + q];
        pr[8 * q + 0] = blo(P.x); pr[8 * q + 1] = bhi(P.x);
        pr[8 * q + 2] = blo(P.y); pr[8 * q + 3] = bhi(P.y);
        pr[8 * q + 4] = blo(P.z); pr[8 * q + 5] = bhi(P.z);
        pr[8 * q + 6] = blo(P.w); pr[8 * q + 7] = bhi(P.w);
    }
#pragma unroll
    for (int k4 = 0; k4 < 8; k4++) {
        float4 a = h1v[k4];
        float av[4] = {a.x, a.y, a.z, a.w};
#pragma unroll
        for (int s = 0; s < 4; s++) {
            int k = k4 * 4 + s;
            float aa = av[s], pp = pr[k];
#pragma unroll
            for (int j4 = 0; j4 < 16; j4++) {
                float4 w0r = w0v[k * 16 + j4];
                float4 w1r = w1v[k * 16 + j4];
                acc[j4].x += aa * w0r.x + pp * w1r.x;
                acc[j4].y += aa * w0r.y + pp * w1r.y;
                acc[j4].z += aa * w0r.z + pp * w1r.z;
                acc[j4].w += aa * w0r.w + pp * w1r.w;
            }
        }
    }
    float4* out = (float4*)(h2 + (long)i * 64);
#pragma unroll
    for (int j4 = 0; j4 < 16; j4++) {
        float4 v = acc[j4];
        v.x = v.x > 0.f ? v.x : v.x * NEG_SLOPE;
        v.y = v.y > 0.f ? v.y : v.y * NEG_SLOPE;
        v.z = v.z > 0.f ? v.z : v.z * NEG_SLOPE;
        v.w = v.w > 0.f ? v.w : v.w * NEG_SLOPE;
        out[j4] = v;
    }
}

// ---- fused pooled sums over h2 ------------------------------------------
// sbuf[j]    += sum_i h2[i][j]
// sbuf[64+j] += sum_i (presum[i]*dinv[i]) * h2[i][j]   (cw = presum*dinv)
__global__ void sum2_kernel(const float* __restrict__ h2, const float* __restrict__ presum,
                            const float* __restrict__ dinv, float* __restrict__ sbuf, long total) {
    long tid = (long)blockIdx.x * blockDim.x + threadIdx.x;
    long stride = (long)gridDim.x * blockDim.x;   // multiple of 64
    float a1 = 0.f, a2 = 0.f;
    for (long idx = tid; idx < total; idx += stride) {
        float v = h2[idx];
        long i = idx >> 6;
        a1 += v;
        a2 += presum[i] * dinv[i] * v;
    }
    __shared__ float red1[256];
    __shared__ float red2[256];
    red1[threadIdx.x] = a1;
    red2[threadIdx.x] = a2;
    __syncthreads();
    if (threadIdx.x < 64) {
        float s1 = red1[threadIdx.x] + red1[threadIdx.x + 64] + red1[threadIdx.x + 128] + red1[threadIdx.x + 192];
        float s2 = red2[threadIdx.x] + red2[threadIdx.x + 64] + red2[threadIdx.x + 128] + red2[threadIdx.x + 192];
        atomAddF(&sbuf[threadIdx.x], s1);
        atomAddF(&sbuf[64 + threadIdx.x], s2);
    }
}

// ---- pooled = (s1/N)@w30 + (s2/N)@w31 + b3; out = log_softmax -----------
__global__ void final_kernel(const float* __restrict__ sbuf,
                             const float* __restrict__ w30, const float* __restrict__ w31,
                             const float* __restrict__ b3, float* __restrict__ out, float invN) {
    if (threadIdx.x != 0 || blockIdx.x != 0) return;
    const float* s1 = sbuf;
    const float* s2 = sbuf + 64;
    float p[2];
    for (int c = 0; c < 2; c++) {
        float a = 0.f;
        for (int k = 0; k < 64; k++) a += s1[k] * w30[k * 2 + c] + s2[k] * w31[k * 2 + c];
        p[c] = a * invN + b3[c];
    }
    float m = fmaxf(p[0], p[1]);
    float lse = m + logf(expf(p[0] - m) + expf(p[1] - m));
    out[0] = p[0] - lse;
    out[1] = p[1] - lse;
}

extern "C" void kernel_launch(void* const* d_in, const int* in_sizes, int n_in,
                              void* d_out, int out_size, void* d_ws, size_t ws_size,
                              hipStream_t stream) {
    const float* x    = (const float*)d_in[0];
    const int*   ei   = (const int*)d_in[1];
    const float* attr = (const float*)d_in[2];
    const float* w1_0 = (const float*)d_in[3];
    const float* b1   = (const float*)d_in[4];
    const float* w2_0 = (const float*)d_in[5];
    const float* w2_1 = (const float*)d_in[6];
    const float* b2   = (const float*)d_in[7];
    const float* w3_0 = (const float*)d_in[8];
    const float* w3_1 = (const float*)d_in[9];
    const float* b3   = (const float*)d_in[10];

    const int N = in_sizes[0] / 20;   // 100000
    const int E = in_sizes[2];        // 3200000
    const int* row = ei;
    const int* col = ei + E;
    const int NB = (N + 255) >> 8;    // 391 buckets (<= 512)

    // workspace layout (words)
    long big = (long)(2L * E > 64L * N ? 2L * E : 64L * N);
    float* ws = (float*)d_ws;
    float* dinv   = ws;                            // N
    float* presum = ws + N;                        // N
    int*   rowptr = (int*)(ws + 2L * N);           // N+1 (alloc N+4)
    long   off    = 3L * N + 4;
    int*   bhR    = (int*)(ws + off); off += 512L * PAD;   // row hist (padded)
    int*   bhC    = (int*)(ws + off); off += 512L * PAD;   // col hist (padded)
    int*   bbaseR = (int*)(ws + off); off += 516;
    int*   bbaseC = (int*)(ws + off); off += 516;
    int*   bcurR  = (int*)(ws + off); off += 512L * PAD;
    int*   bcurC  = (int*)(ws + off); off += 512L * PAD;
    float* sbuf   = ws + off;         off += 128;
    long   offA   = (off + 15) & ~15L;                     // 64B-align regA
    float* regA   = ws + offA;                  // big: stagingR, then h1+p1b+h1b
    float* regB   = regA + big;                 // big: stagingC, then sorted, then h2

    int2*  stagingR = (int2*)regA;              // dead after rowsort (4c)
    float* h1       = regA;                     // fp32, 32N words
    uint4* p1b      = (uint4*)(regA + 32L * N); // bf16, 16N words
    uint4* h1b      = (uint4*)(regA + 48L * N); // bf16 (dinv-scaled), 16N words
    int2*  stagingC = (int2*)regB;              // dead after col_finalize (4b)
    int2*  sorted   = (int2*)regB;              // written in 4c, dead after gather
    float* h2       = regB;                     // overlays sorted after gather

    // zero accumulated regions (ws is poisoned before every launch)
    hipMemsetAsync(bhR, 0, 2 * 512 * PAD * 4, stream);   // bhR + bhC contiguous
    hipMemsetAsync(sbuf, 0, 128 * 4, stream);

    const int B = 256;
    const int NCH = (E + CH - 1) / CH;   // chunk-blocks for hist/scatter
    hist2_kernel<<<NCH, B, 0, stream>>>(row, col, bhR, bhC, E, NB);
    bucket_scan_kernel<<<1, 512, 0, stream>>>(bhR, bbaseR, bcurR, rowptr, NB, N, E);
    bucket_scan_kernel<<<1, 512, 0, stream>>>(bhC, bbaseC, bcurC, rowptr, NB, N, E);
    scatter2_kernel<<<NCH, B, 0, stream>>>(row, col, attr, bcurR, bcurC, stagingR, stagingC, E, NB);
    rowdeg_kernel<<<NB, 256, 0, stream>>>(bbaseR, stagingR, rowptr, dinv, N);
    col_finalize_kernel<<<NB, 256, 0, stream>>>(bbaseC, stagingC, dinv, presum, N);
    rowsort_kernel<<<NB, 256, 0, stream>>>(bbaseR, stagingR, dinv, sorted, N);
    h1_kernel<<<(N + B - 1) / B, B, 0, stream>>>(x, w1_0, b1, dinv, h1, h1b, N);
    {
        long t = (long)N * 4;
        gather_kernel<<<(int)((t + B - 1) / B), B, 0, stream>>>(rowptr, sorted, h1b, p1b, N);
    }
    h2_kernel<<<(N + B - 1) / B, B, 0, stream>>>(h1, p1b, w2_0, w2_1, b2, h2, N);
    sum2_kernel<<<256, B, 0, stream>>>(h2, presum, dinv, sbuf, (long)N * 64);
    final_kernel<<<1, 64, 0, stream>>>(sbuf, w3_0, w3_1, b3, (float*)d_out, 1.0f / (float)N);
}